// Round 21
// baseline (195.920 us; speedup 1.0000x reference)
//
#include <hip/hip_runtime.h>
#include <hip/hip_bf16.h>
#include <stdint.h>

#define M_DIM 8192   // 4*2048
#define N_DIM 4096   // OUT_FEATURES
#define K_DIM 4096   // IN_FEATURES

typedef __attribute__((ext_vector_type(4))) float f32x4;
typedef __attribute__((ext_vector_type(4))) int   i32x4;

#define GLD_LDS16(gaddr, laddr)                                            \
  __builtin_amdgcn_global_load_lds(                                        \
      (const __attribute__((address_space(1))) uint32_t*)(gaddr),          \
      (__attribute__((address_space(3))) uint32_t*)(laddr), 16, 0, 0)

// ---------------------------------------------------------------------------
// i8 subtile-major layout (BK=64), unchanged from R16:
//  t = k>>6 (64 K-tiles); rp = row>>8; h = (row>>7)&1; f = (row>>4)&7;
//  lane slot l = (row&15) + ((k>>4)&3)*16 ; byte-in-slot = k&15
//  byte = (rp*64 + t)*16384 + h*8192 + f*1024 + l*16 + (k&15)
// ---------------------------------------------------------------------------

// Merged prep (UNCHANGED from R16): [0,2048): W dequant->i8; [2048,10240): x.
__global__ __launch_bounds__(256) void prep_kernel(
    const int* __restrict__ q, const float* __restrict__ lut,
    signed char* __restrict__ Wq, float* __restrict__ sw,
    const float* __restrict__ x, signed char* __restrict__ Xq,
    float* __restrict__ sxd) {
  __shared__ char sm[16384];
  const int b = blockIdx.x;
  const int tid = threadIdx.x;
  if (b < 2048) {
    const int ob = b >> 4, wb = b & 15;
    const int o_l = tid >> 3, w_l = tid & 7;
    const int o = ob * 32 + o_l;
    const int PLANE = N_DIM * (K_DIM / 32);
    const int base = o * (K_DIM / 32) + wb * 8 + w_l;
    uint32_t q0 = (uint32_t)q[base];
    uint32_t q1 = (uint32_t)q[PLANE + base];
    uint32_t q2 = (uint32_t)q[2 * PLANE + base];
    uint32_t q3 = (uint32_t)q[3 * PLANE + base];
    const float* lrow = lut + o * 16;
    float lmax = 1e-30f;
#pragma unroll
    for (int j = 0; j < 16; ++j) lmax = fmaxf(lmax, fabsf(lrow[j]));
    const float qs = 127.0f / lmax;
    signed char l8[16];
#pragma unroll
    for (int j = 0; j < 16; ++j)
      l8[j] = (signed char)(int)rintf(lrow[j] * qs);
    if (wb == 0 && w_l == 0) sw[o] = lmax * (1.0f / 127.0f);

    union { i32x4 v; signed char c[16]; } u0, u1;
#pragma unroll
    for (int i = 0; i < 16; ++i) {
      uint32_t idx = ((q0 >> i) & 1u) | (((q1 >> i) & 1u) << 1) |
                     (((q2 >> i) & 1u) << 2) | (((q3 >> i) & 1u) << 3);
      u0.c[i] = l8[idx];
    }
#pragma unroll
    for (int i = 16; i < 32; ++i) {
      uint32_t idx = ((q0 >> i) & 1u) | (((q1 >> i) & 1u) << 1) |
                     (((q2 >> i) & 1u) << 2) | (((q3 >> i) & 1u) << 3);
      u1.c[i - 16] = l8[idx];
    }
    const int t_local = w_l >> 1;            // 0..3
    const int f_local = o_l >> 4;            // 0..1
    const int kc0 = (w_l & 1) * 2;           // 0 or 2
    char* sp = sm + t_local * 2048 + f_local * 1024;
    *(i32x4*)(sp + ((o_l & 15) + kc0 * 16) * 16)       = u0.v;
    *(i32x4*)(sp + ((o_l & 15) + (kc0 + 1) * 16) * 16) = u1.v;
    __syncthreads();
    const int rp = ob >> 3, h = (ob >> 2) & 1, f0 = (ob * 2) & 7;
#pragma unroll
    for (int c = 0; c < 2; ++c) {
      const int ci = c * 256 + tid;          // 0..511 slots of 16B
      const int t_loc = ci >> 7, off = ci & 127;
      const size_t outb = (size_t)(rp * 64 + wb * 4 + t_loc) * 16384
                          + h * 8192 + f0 * 1024 + off * 16;
      *(i32x4*)(Wq + outb) = *(i32x4*)(sm + t_loc * 2048 + off * 16);
    }
  } else {
    const int r = b - 2048;
    const float* xr = x + (size_t)r * K_DIM;
    float v[16];
#pragma unroll
    for (int s = 0; s < 4; ++s) {
      f32x4 u = *(const f32x4*)(xr + tid * 4 + s * 1024);
      v[s * 4 + 0] = u[0]; v[s * 4 + 1] = u[1];
      v[s * 4 + 2] = u[2]; v[s * 4 + 3] = u[3];
    }
    float m = 0.0f;
#pragma unroll
    for (int i = 0; i < 16; ++i) m = fmaxf(m, fabsf(v[i]));
#pragma unroll
    for (int off = 32; off; off >>= 1) m = fmaxf(m, __shfl_down(m, off));
    float* red = (float*)(sm + 8192);
    if ((tid & 63) == 0) red[tid >> 6] = m;
    __syncthreads();
    float rmax = fmaxf(fmaxf(red[0], red[1]), fmaxf(red[2], red[3]));
    rmax = fmaxf(rmax, 1e-30f);
    if (tid == 0) sxd[r] = rmax * (1.0f / 127.0f);
    const float qs = 127.0f / rmax;
#pragma unroll
    for (int s = 0; s < 4; ++s) {
      int qi[4];
#pragma unroll
      for (int j = 0; j < 4; ++j) {
        float qc = fminf(127.0f, fmaxf(-127.0f, rintf(v[s * 4 + j] * qs)));
        qi[j] = (int)qc;
      }
      uint32_t w = (qi[0] & 255) | ((qi[1] & 255) << 8) |
                   ((qi[2] & 255) << 16) | ((uint32_t)(qi[3] & 255) << 24);
      *(uint32_t*)(sm + tid * 4 + s * 1024) = w;
    }
    __syncthreads();
    const int rp = r >> 8, h = (r >> 7) & 1, f = (r >> 4) & 7;
    const int kt = tid >> 2, kc = tid & 3;
    const size_t outb = (size_t)(rp * 64 + kt) * 16384 + h * 8192
                        + f * 1024 + ((r & 15) + kc * 16) * 16;
    *(i32x4*)(Xq + outb) = *(i32x4*)(sm + tid * 16);
  }
}

// ---------------------------------------------------------------------------
// 256x256 i8 GEMM, R21 = ring-of-4 (1 barrier + 1 cert / tile) + FULL
// one-phase-ahead register prefetch (R16's read-ahead).
// Phase t (rb=t&3, rn=(t+1)&3):
//   STAGE(t+3) into buf (t+3)&3 [= buf of t-1; reads drained at t-1's bar]
//   LDA a1(t) ; MMA(0,0) MMA(0,1)          [a0,b0,b1 preloaded in t-1]
//   LDA a0(t+1) ; MMA(1,1) ; LDB b1(t+1) ; MMA(1,0) ; LDB b0(t+1)
//     [tile t+1 certified at end of t-1 -> reads legal, hidden under MFMA]
//   LGKM0 ; VMC(4) [certifies t+2, staged 2 phases ago] ; BAR
// Prologue: stage 0,1,2; VMC(4) certifies tiles 0 AND 1; preload t0 frags.
// ---------------------------------------------------------------------------
__global__ __launch_bounds__(512, 2) void anyprec_gemm_kernel(
    const signed char* __restrict__ A,   // Xq subtile-major
    const signed char* __restrict__ B,   // Wq subtile-major
    const float* __restrict__ sxd, const float* __restrict__ sw,
    const float* __restrict__ bias,
    float* __restrict__ C) {
  __shared__ char lds[4][32768];   // ring: A tile 16KB at +0, B at +16384

  int bid = blockIdx.x;
  int swz = (bid & 7) * 64 + (bid >> 3);
  int mb = swz >> 4;    // 32 m-tiles
  int nb = swz & 15;    // 16 n-tiles

  const int tid  = threadIdx.x;
  const int lane = tid & 63;
  const int wid  = tid >> 6;
  const int wr   = wid >> 2;   // 0..1
  const int wc   = wid & 3;    // 0..3
  const int tid16  = tid * 16;
  const int lane16 = lane * 16;

  char* lbase = &lds[0][0];

  const char* gA = (const char*)A + (size_t)mb * 1048576;  // 64 tiles * 16KB
  const char* gB = (const char*)B + (size_t)nb * 1048576;

  i32x4 acc[2][2][4][2];
#pragma unroll
  for (int qm = 0; qm < 2; ++qm)
#pragma unroll
    for (int qn = 0; qn < 2; ++qn)
#pragma unroll
      for (int mf = 0; mf < 4; ++mf)
#pragma unroll
        for (int nf = 0; nf < 2; ++nf) acc[qm][qn][mf][nf] = (i32x4)0;

  i32x4 a0[4], a1[4], b0[2], b1[2];

#define STAGE_T(t, rb) {                                                   \
    char* lb_ = lbase + (rb) * 32768 + tid16;                              \
    const char* ga_ = gA + (size_t)(t) * 16384 + tid16;                    \
    const char* gb_ = gB + (size_t)(t) * 16384 + tid16;                    \
    GLD_LDS16(ga_,        lb_);                                            \
    GLD_LDS16(ga_ + 8192, lb_ + 8192);                                     \
    GLD_LDS16(gb_,        lb_ + 16384);                                    \
    GLD_LDS16(gb_ + 8192, lb_ + 24576); }

// A: row = qm*128 + wr*64 + mf*16 -> h=qm, f=wr*4+mf; A at buf+0
#define LDA(dst, qm, rb) {                                                 \
    const char* p_ = lbase + (rb) * 32768 + (qm) * 8192 + wr * 4096        \
                     + lane16;                                             \
    _Pragma("unroll")                                                      \
    for (int mf = 0; mf < 4; ++mf)                                         \
      dst[mf] = *(const i32x4*)(p_ + mf * 1024); }

// B: col = qn*128 + wc*32 + nf*16 -> h=qn, f=wc*2+nf; B at buf+16384
#define LDB(dst, qn, rb) {                                                 \
    const char* p_ = lbase + (rb) * 32768 + 16384 + (qn) * 8192            \
                     + wc * 2048 + lane16;                                 \
    _Pragma("unroll")                                                      \
    for (int nf = 0; nf < 2; ++nf)                                         \
      dst[nf] = *(const i32x4*)(p_ + nf * 1024); }

#define MMA(qm, qn, aa, bb) {                                              \
    _Pragma("unroll")                                                      \
    for (int mf = 0; mf < 4; ++mf)                                         \
      _Pragma("unroll")                                                    \
      for (int nf = 0; nf < 2; ++nf)                                       \
        acc[qm][qn][mf][nf] = __builtin_amdgcn_mfma_i32_16x16x64_i8(       \
            aa[mf], bb[nf], acc[qm][qn][mf][nf], 0, 0, 0); }

#define PRIO1 __builtin_amdgcn_s_setprio(1);
#define PRIO0 __builtin_amdgcn_s_setprio(0);
#define BAR   __builtin_amdgcn_s_barrier();
#define LGKM0 asm volatile("s_waitcnt lgkmcnt(0)" ::: "memory");
#define VMC(n) asm volatile("s_waitcnt vmcnt(" #n ")" ::: "memory");

  // ---- prologue: stage tiles 0,1,2; certify tiles 0 AND 1; preload t0 frags
  STAGE_T(0, 0);
  STAGE_T(1, 1);
  STAGE_T(2, 2);
  VMC(4); BAR;                  // drains tiles 0,1 (leaves tile2's 4 loads)
  LDA(a0, 0, 0); LDB(b0, 0, 0); LDB(b1, 1, 0);

  // ---- main loop: t = 0..60 (stage t+3 <= 63)
  for (int t = 0; t < 61; ++t) {
    const int rb = t & 3, rn = (t + 1) & 3;
    STAGE_T(t + 3, (t + 3) & 3);
    PRIO1;
    LDA(a1, 1, rb);
    MMA(0, 0, a0, b0); MMA(0, 1, a0, b1);
    LDA(a0, 0, rn);                 // tile t+1 (certified end of t-1)
    MMA(1, 1, a1, b1); LDB(b1, 1, rn);
    MMA(1, 0, a1, b0); LDB(b0, 0, rn);
    PRIO0;
    LGKM0;                          // all reads drained -> WAR collective-safe
    VMC(4);                         // certify tile t+2 (staged 2 phases ago)
    BAR;
  }
  // ---- t = 61: no stage; certify tile 63 fully (VMC(0))
  {
    PRIO1;
    LDA(a1, 1, 1);
    MMA(0, 0, a0, b0); MMA(0, 1, a0, b1);
    LDA(a0, 0, 2);
    MMA(1, 1, a1, b1); LDB(b1, 1, 2);
    MMA(1, 0, a1, b0); LDB(b0, 0, 2);
    PRIO0;
    LGKM0; VMC(0); BAR;
  }
  // ---- t = 62: no stage, no barrier (everything certified)
  {
    PRIO1;
    LDA(a1, 1, 2);
    MMA(0, 0, a0, b0); MMA(0, 1, a0, b1);
    LDA(a0, 0, 3);
    MMA(1, 1, a1, b1); LDB(b1, 1, 3);
    MMA(1, 0, a1, b0); LDB(b0, 0, 3);
    PRIO0;
  }
  // ---- t = 63
  {
    PRIO1;
    LDA(a1, 1, 3);
    MMA(0, 0, a0, b0); MMA(0, 1, a0, b1);
    MMA(1, 1, a1, b1); MMA(1, 0, a1, b0);
    PRIO0;
  }

  // ---- epilogue: C/D layout col=lane&15, row=(lane>>4)*4+j (dtype-indep)
  const int cL = lane & 15;
  const int rL = (lane >> 4) * 4;
#pragma unroll
  for (int qn = 0; qn < 2; ++qn)
#pragma unroll
    for (int nf = 0; nf < 2; ++nf) {
      int col = nb * 256 + qn * 128 + wc * 32 + nf * 16 + cL;
      float bv  = bias[col];
      float swc = sw[col];
#pragma unroll
      for (int qm = 0; qm < 2; ++qm)
#pragma unroll
        for (int mf = 0; mf < 4; ++mf) {
          int row0 = mb * 256 + qm * 128 + wr * 64 + mf * 16 + rL;
#pragma unroll
          for (int j = 0; j < 4; ++j) {
            int row = row0 + j;
            float s = sxd[row] * swc;
            C[(size_t)row * N_DIM + col] =
                fmaf((float)acc[qm][qn][mf][nf][j], s, bv);
          }
        }
    }
#undef STAGE_T
#undef LDA
#undef LDB
#undef MMA
#undef PRIO1
#undef PRIO0
#undef BAR
#undef LGKM0
#undef VMC
}

extern "C" void kernel_launch(void* const* d_in, const int* in_sizes, int n_in,
                              void* d_out, int out_size, void* d_ws, size_t ws_size,
                              hipStream_t stream) {
  const float* x    = (const float*)d_in[0];
  const int*   qw   = (const int*)d_in[1];
  const float* lut  = (const float*)d_in[2];
  const float* bias = (const float*)d_in[3];

  char* wsb = (char*)d_ws;
  signed char* Wq  = (signed char*)wsb;                         // 16 MB
  signed char* Xq  = (signed char*)(wsb + (size_t)16 * 1024 * 1024);  // 32 MB
  float*       sxd = (float*)(wsb + (size_t)48 * 1024 * 1024);  // 32 KB
  float*       sw  = sxd + M_DIM;                               // 16 KB

  {
    prep_kernel<<<10240, 256, 0, stream>>>(qw, lut, Wq, sw, x, Xq, sxd);
  }
  {
    dim3 grid((M_DIM / 256) * (N_DIM / 256));  // 32*16 = 512
    anyprec_gemm_kernel<<<grid, 512, 0, stream>>>(Xq, Wq, sxd, sw, bias,
                                                  (float*)d_out);
  }
}

// Round 22
// 193.207 us; speedup vs baseline: 1.0140x; 1.0140x over previous
//
#include <hip/hip_runtime.h>
#include <hip/hip_bf16.h>
#include <stdint.h>

#define M_DIM 8192   // 4*2048
#define N_DIM 4096   // OUT_FEATURES
#define K_DIM 4096   // IN_FEATURES

typedef __attribute__((ext_vector_type(4))) float f32x4;
typedef __attribute__((ext_vector_type(4))) int   i32x4;

#define GLD_LDS16(gaddr, laddr)                                            \
  __builtin_amdgcn_global_load_lds(                                        \
      (const __attribute__((address_space(1))) uint32_t*)(gaddr),          \
      (__attribute__((address_space(3))) uint32_t*)(laddr), 16, 0, 0)

// ---------------------------------------------------------------------------
// i8 subtile-major layout (BK=64), unchanged from R16:
//  t = k>>6 (64 K-tiles); rp = row>>8; h = (row>>7)&1; f = (row>>4)&7;
//  lane slot l = (row&15) + ((k>>4)&3)*16 ; byte-in-slot = k&15
//  byte = (rp*64 + t)*16384 + h*8192 + f*1024 + l*16 + (k&15)
// ---------------------------------------------------------------------------

// Merged prep (UNCHANGED from R16): [0,2048): W dequant->i8; [2048,10240): x.
__global__ __launch_bounds__(256) void prep_kernel(
    const int* __restrict__ q, const float* __restrict__ lut,
    signed char* __restrict__ Wq, float* __restrict__ sw,
    const float* __restrict__ x, signed char* __restrict__ Xq,
    float* __restrict__ sxd) {
  __shared__ char sm[16384];
  const int b = blockIdx.x;
  const int tid = threadIdx.x;
  if (b < 2048) {
    const int ob = b >> 4, wb = b & 15;
    const int o_l = tid >> 3, w_l = tid & 7;
    const int o = ob * 32 + o_l;
    const int PLANE = N_DIM * (K_DIM / 32);
    const int base = o * (K_DIM / 32) + wb * 8 + w_l;
    uint32_t q0 = (uint32_t)q[base];
    uint32_t q1 = (uint32_t)q[PLANE + base];
    uint32_t q2 = (uint32_t)q[2 * PLANE + base];
    uint32_t q3 = (uint32_t)q[3 * PLANE + base];
    const float* lrow = lut + o * 16;
    float lmax = 1e-30f;
#pragma unroll
    for (int j = 0; j < 16; ++j) lmax = fmaxf(lmax, fabsf(lrow[j]));
    const float qs = 127.0f / lmax;
    signed char l8[16];
#pragma unroll
    for (int j = 0; j < 16; ++j)
      l8[j] = (signed char)(int)rintf(lrow[j] * qs);
    if (wb == 0 && w_l == 0) sw[o] = lmax * (1.0f / 127.0f);

    union { i32x4 v; signed char c[16]; } u0, u1;
#pragma unroll
    for (int i = 0; i < 16; ++i) {
      uint32_t idx = ((q0 >> i) & 1u) | (((q1 >> i) & 1u) << 1) |
                     (((q2 >> i) & 1u) << 2) | (((q3 >> i) & 1u) << 3);
      u0.c[i] = l8[idx];
    }
#pragma unroll
    for (int i = 16; i < 32; ++i) {
      uint32_t idx = ((q0 >> i) & 1u) | (((q1 >> i) & 1u) << 1) |
                     (((q2 >> i) & 1u) << 2) | (((q3 >> i) & 1u) << 3);
      u1.c[i - 16] = l8[idx];
    }
    const int t_local = w_l >> 1;            // 0..3
    const int f_local = o_l >> 4;            // 0..1
    const int kc0 = (w_l & 1) * 2;           // 0 or 2
    char* sp = sm + t_local * 2048 + f_local * 1024;
    *(i32x4*)(sp + ((o_l & 15) + kc0 * 16) * 16)       = u0.v;
    *(i32x4*)(sp + ((o_l & 15) + (kc0 + 1) * 16) * 16) = u1.v;
    __syncthreads();
    const int rp = ob >> 3, h = (ob >> 2) & 1, f0 = (ob * 2) & 7;
#pragma unroll
    for (int c = 0; c < 2; ++c) {
      const int ci = c * 256 + tid;          // 0..511 slots of 16B
      const int t_loc = ci >> 7, off = ci & 127;
      const size_t outb = (size_t)(rp * 64 + wb * 4 + t_loc) * 16384
                          + h * 8192 + f0 * 1024 + off * 16;
      *(i32x4*)(Wq + outb) = *(i32x4*)(sm + t_loc * 2048 + off * 16);
    }
  } else {
    const int r = b - 2048;
    const float* xr = x + (size_t)r * K_DIM;
    float v[16];
#pragma unroll
    for (int s = 0; s < 4; ++s) {
      f32x4 u = *(const f32x4*)(xr + tid * 4 + s * 1024);
      v[s * 4 + 0] = u[0]; v[s * 4 + 1] = u[1];
      v[s * 4 + 2] = u[2]; v[s * 4 + 3] = u[3];
    }
    float m = 0.0f;
#pragma unroll
    for (int i = 0; i < 16; ++i) m = fmaxf(m, fabsf(v[i]));
#pragma unroll
    for (int off = 32; off; off >>= 1) m = fmaxf(m, __shfl_down(m, off));
    float* red = (float*)(sm + 8192);
    if ((tid & 63) == 0) red[tid >> 6] = m;
    __syncthreads();
    float rmax = fmaxf(fmaxf(red[0], red[1]), fmaxf(red[2], red[3]));
    rmax = fmaxf(rmax, 1e-30f);
    if (tid == 0) sxd[r] = rmax * (1.0f / 127.0f);
    const float qs = 127.0f / rmax;
#pragma unroll
    for (int s = 0; s < 4; ++s) {
      int qi[4];
#pragma unroll
      for (int j = 0; j < 4; ++j) {
        float qc = fminf(127.0f, fmaxf(-127.0f, rintf(v[s * 4 + j] * qs)));
        qi[j] = (int)qc;
      }
      uint32_t w = (qi[0] & 255) | ((qi[1] & 255) << 8) |
                   ((qi[2] & 255) << 16) | ((uint32_t)(qi[3] & 255) << 24);
      *(uint32_t*)(sm + tid * 4 + s * 1024) = w;
    }
    __syncthreads();
    const int rp = r >> 8, h = (r >> 7) & 1, f = (r >> 4) & 7;
    const int kt = tid >> 2, kc = tid & 3;
    const size_t outb = (size_t)(rp * 64 + kt) * 16384 + h * 8192
                        + f * 1024 + ((r & 15) + kc * 16) * 16;
    *(i32x4*)(Xq + outb) = *(i32x4*)(sm + tid * 16);
  }
}

// ---------------------------------------------------------------------------
// 256x256 i8 GEMM, R22 = R21 ring-of-4 WITHOUT the LGKM0 force-drains.
// WAR safety without lgkm waits (ledger): buf (t+3)&3's last readers are
// prefetch reads of tile t-1 (issued t-2) and a1-reads (issued t-1) -- ALL
// consumed by MFMAs before the end-of-(t-1) barrier (consumed => complete),
// which the barrier collectivizes. Ring depth 4 gives every read >=1 full
// barrier of slack before its buffer is re-staged. The per-phase VMC(4)
// ("memory" clobber) pins compiler ordering and certifies tile t+2
// (staged 2 phases ~5000 cyc earlier). Prefetch reads now genuinely drain
// under the NEXT phase's 32-MFMA cluster -> pipes overlap.
// ---------------------------------------------------------------------------
__global__ __launch_bounds__(512, 2) void anyprec_gemm_kernel(
    const signed char* __restrict__ A,   // Xq subtile-major
    const signed char* __restrict__ B,   // Wq subtile-major
    const float* __restrict__ sxd, const float* __restrict__ sw,
    const float* __restrict__ bias,
    float* __restrict__ C) {
  __shared__ char lds[4][32768];   // ring: A tile 16KB at +0, B at +16384

  int bid = blockIdx.x;
  int swz = (bid & 7) * 64 + (bid >> 3);
  int mb = swz >> 4;    // 32 m-tiles
  int nb = swz & 15;    // 16 n-tiles

  const int tid  = threadIdx.x;
  const int lane = tid & 63;
  const int wid  = tid >> 6;
  const int wr   = wid >> 2;   // 0..1
  const int wc   = wid & 3;    // 0..3
  const int tid16  = tid * 16;
  const int lane16 = lane * 16;

  char* lbase = &lds[0][0];

  const char* gA = (const char*)A + (size_t)mb * 1048576;  // 64 tiles * 16KB
  const char* gB = (const char*)B + (size_t)nb * 1048576;

  i32x4 acc[2][2][4][2];
#pragma unroll
  for (int qm = 0; qm < 2; ++qm)
#pragma unroll
    for (int qn = 0; qn < 2; ++qn)
#pragma unroll
      for (int mf = 0; mf < 4; ++mf)
#pragma unroll
        for (int nf = 0; nf < 2; ++nf) acc[qm][qn][mf][nf] = (i32x4)0;

  i32x4 a0[4], a1[4], b0[2], b1[2];

#define STAGE_T(t, rb) {                                                   \
    char* lb_ = lbase + (rb) * 32768 + tid16;                              \
    const char* ga_ = gA + (size_t)(t) * 16384 + tid16;                    \
    const char* gb_ = gB + (size_t)(t) * 16384 + tid16;                    \
    GLD_LDS16(ga_,        lb_);                                            \
    GLD_LDS16(ga_ + 8192, lb_ + 8192);                                     \
    GLD_LDS16(gb_,        lb_ + 16384);                                    \
    GLD_LDS16(gb_ + 8192, lb_ + 24576); }

// A: row = qm*128 + wr*64 + mf*16 -> h=qm, f=wr*4+mf; A at buf+0
#define LDA(dst, qm, rb) {                                                 \
    const char* p_ = lbase + (rb) * 32768 + (qm) * 8192 + wr * 4096        \
                     + lane16;                                             \
    _Pragma("unroll")                                                      \
    for (int mf = 0; mf < 4; ++mf)                                         \
      dst[mf] = *(const i32x4*)(p_ + mf * 1024); }

// B: col = qn*128 + wc*32 + nf*16 -> h=qn, f=wc*2+nf; B at buf+16384
#define LDB(dst, qn, rb) {                                                 \
    const char* p_ = lbase + (rb) * 32768 + 16384 + (qn) * 8192            \
                     + wc * 2048 + lane16;                                 \
    _Pragma("unroll")                                                      \
    for (int nf = 0; nf < 2; ++nf)                                         \
      dst[nf] = *(const i32x4*)(p_ + nf * 1024); }

#define MMA(qm, qn, aa, bb) {                                              \
    _Pragma("unroll")                                                      \
    for (int mf = 0; mf < 4; ++mf)                                         \
      _Pragma("unroll")                                                    \
      for (int nf = 0; nf < 2; ++nf)                                       \
        acc[qm][qn][mf][nf] = __builtin_amdgcn_mfma_i32_16x16x64_i8(       \
            aa[mf], bb[nf], acc[qm][qn][mf][nf], 0, 0, 0); }

#define PRIO1 __builtin_amdgcn_s_setprio(1);
#define PRIO0 __builtin_amdgcn_s_setprio(0);
#define BAR   __builtin_amdgcn_s_barrier();
#define VMC(n) asm volatile("s_waitcnt vmcnt(" #n ")" ::: "memory");

  // ---- prologue: stage tiles 0,1,2; certify tiles 0 AND 1; preload t0 frags
  STAGE_T(0, 0);
  STAGE_T(1, 1);
  STAGE_T(2, 2);
  VMC(4); BAR;                  // drains tiles 0,1 (leaves tile2's 4 loads)
  LDA(a0, 0, 0); LDB(b0, 0, 0); LDB(b1, 1, 0);

  // ---- main loop: t = 0..60 (stage t+3 <= 63); NO lgkm drains
  for (int t = 0; t < 61; ++t) {
    const int rb = t & 3, rn = (t + 1) & 3;
    STAGE_T(t + 3, (t + 3) & 3);
    PRIO1;
    LDA(a1, 1, rb);
    MMA(0, 0, a0, b0); MMA(0, 1, a0, b1);
    LDA(a0, 0, rn);                 // tile t+1 (certified end of t-1)
    MMA(1, 1, a1, b1); LDB(b1, 1, rn);
    MMA(1, 0, a1, b0); LDB(b0, 0, rn);
    PRIO0;
    VMC(4);                         // certify tile t+2 (staged 2 phases ago)
    BAR;
  }
  // ---- t = 61: no stage; certify tile 63 fully
  {
    PRIO1;
    LDA(a1, 1, 1);
    MMA(0, 0, a0, b0); MMA(0, 1, a0, b1);
    LDA(a0, 0, 2);
    MMA(1, 1, a1, b1); LDB(b1, 1, 2);
    MMA(1, 0, a1, b0); LDB(b0, 0, 2);
    PRIO0;
    VMC(0); BAR;
  }
  // ---- t = 62: no stage, no barrier (everything certified)
  {
    PRIO1;
    LDA(a1, 1, 2);
    MMA(0, 0, a0, b0); MMA(0, 1, a0, b1);
    LDA(a0, 0, 3);
    MMA(1, 1, a1, b1); LDB(b1, 1, 3);
    MMA(1, 0, a1, b0); LDB(b0, 0, 3);
    PRIO0;
  }
  // ---- t = 63
  {
    PRIO1;
    LDA(a1, 1, 3);
    MMA(0, 0, a0, b0); MMA(0, 1, a0, b1);
    MMA(1, 1, a1, b1); MMA(1, 0, a1, b0);
    PRIO0;
  }

  // ---- epilogue: C/D layout col=lane&15, row=(lane>>4)*4+j (dtype-indep)
  const int cL = lane & 15;
  const int rL = (lane >> 4) * 4;
#pragma unroll
  for (int qn = 0; qn < 2; ++qn)
#pragma unroll
    for (int nf = 0; nf < 2; ++nf) {
      int col = nb * 256 + qn * 128 + wc * 32 + nf * 16 + cL;
      float bv  = bias[col];
      float swc = sw[col];
#pragma unroll
      for (int qm = 0; qm < 2; ++qm)
#pragma unroll
        for (int mf = 0; mf < 4; ++mf) {
          int row0 = mb * 256 + qm * 128 + wr * 64 + mf * 16 + rL;
#pragma unroll
          for (int j = 0; j < 4; ++j) {
            int row = row0 + j;
            float s = sxd[row] * swc;
            C[(size_t)row * N_DIM + col] =
                fmaf((float)acc[qm][qn][mf][nf][j], s, bv);
          }
        }
    }
#undef STAGE_T
#undef LDA
#undef LDB
#undef MMA
#undef PRIO1
#undef PRIO0
#undef BAR
#undef VMC
}

extern "C" void kernel_launch(void* const* d_in, const int* in_sizes, int n_in,
                              void* d_out, int out_size, void* d_ws, size_t ws_size,
                              hipStream_t stream) {
  const float* x    = (const float*)d_in[0];
  const int*   qw   = (const int*)d_in[1];
  const float* lut  = (const float*)d_in[2];
  const float* bias = (const float*)d_in[3];

  char* wsb = (char*)d_ws;
  signed char* Wq  = (signed char*)wsb;                         // 16 MB
  signed char* Xq  = (signed char*)(wsb + (size_t)16 * 1024 * 1024);  // 32 MB
  float*       sxd = (float*)(wsb + (size_t)48 * 1024 * 1024);  // 32 KB
  float*       sw  = sxd + M_DIM;                               // 16 KB

  {
    prep_kernel<<<10240, 256, 0, stream>>>(qw, lut, Wq, sw, x, Xq, sxd);
  }
  {
    dim3 grid((M_DIM / 256) * (N_DIM / 256));  // 32*16 = 512
    anyprec_gemm_kernel<<<grid, 512, 0, stream>>>(Xq, Wq, sxd, sw, bias,
                                                  (float*)d_out);
  }
}